// Round 4
// baseline (2328.763 us; speedup 1.0000x reference)
//
#include <hip/hip_runtime.h>

// Semi-CRF log-partition. B=4, T=512, L=96, W=63.
// v4: round-3 topology (finalizer block: pair0=d1+merge, pairs d=2,3,4 via LDS;
// relay pairs d=5..63 in 8 interleaved chains) + software pipelining:
//   - depth-4 prefetch of all seg loads (unroll-4, static queue indices)
//   - depth-1 prefetch of axp / chain gate loads (spin-with-reload validates)
//   - split-C publish: per-wave-half C in axp hi-word, consumers rescale 2 groups
// All cross-block handoffs remain single 8B relaxed agent atomics.

#define Tn 512
#define Ln 96
#define LSQ (Ln * Ln)
#define Wn 63
#define KCH 8
#define DMIN 5
#define RPB 4
#define BPB 16
#define PF 4
#define NEGINF (-1e30f)
#define SENT 0x7FC00000u

#define AGENT __HIP_MEMORY_SCOPE_AGENT
#define WG __HIP_MEMORY_SCOPE_WORKGROUP
#define RLX __ATOMIC_RELAXED
#define ACQ __ATOMIC_ACQUIRE
#define REL __ATOMIC_RELEASE

#define SIDX(b, i, t) ((((size_t)(b) * Tn + (i)) * Tn + (t)) * Ln)

typedef unsigned long long u64;
typedef unsigned int u32;

__device__ __forceinline__ float wmaxred(float v) {
#pragma unroll
  for (int m = 32; m >= 1; m >>= 1) v = fmaxf(v, __shfl_xor(v, m, 64));
  return v;
}
__device__ __forceinline__ float wsumred(float v) {
#pragma unroll
  for (int m = 32; m >= 1; m >>= 1) v += __shfl_xor(v, m, 64);
  return v;
}
__device__ __forceinline__ u64 pack2(float lo, float hi) {
  return (u64)__float_as_uint(lo) | ((u64)__float_as_uint(hi) << 32);
}

__global__ void init_ws(u64* ws) {
  const size_t n1 = (size_t)4 * Tn * Ln;
  const size_t n = n1 * (1 + KCH);
  for (size_t i = (size_t)blockIdx.x * blockDim.x + threadIdx.x; i < n;
       i += (size_t)gridDim.x * blockDim.x)
    ws[i] = (i < n1) ? (((u64)SENT) << 32) : 0ull;
}

// split-C combine: c = Cm + wseg + log( e^(C0-Cm)*Slo + e^(C1-Cm)*Shi )
__device__ __forceinline__ float comb(float Slo, float Shi, float C0, float C1,
                                      float wseg) {
  const float Cm = fmaxf(C0, C1);
  return Cm + wseg + __logf(__expf(C0 - Cm) * Slo + __expf(C1 - Cm) * Shi);
}

#define MATVEC(SRC, RR, SLO, SHI)                                          \
  float SLO, SHI;                                                          \
  {                                                                        \
    float i0 = 0, i1 = 0, i2 = 0, i3 = 0, h0 = 0, h1 = 0, h2 = 0, h3 = 0; \
    const float4* A4 = (const float4*)(SRC);                               \
    _Pragma("unroll") for (int q = 0; q < 16; ++q) {                       \
      float4 a = A4[q];                                                    \
      i0 = fmaf(a.x, RR[4 * q + 0], i0);                                   \
      i1 = fmaf(a.y, RR[4 * q + 1], i1);                                   \
      i2 = fmaf(a.z, RR[4 * q + 2], i2);                                   \
      i3 = fmaf(a.w, RR[4 * q + 3], i3);                                   \
    }                                                                      \
    _Pragma("unroll") for (int q = 16; q < 24; ++q) {                      \
      float4 a = A4[q];                                                    \
      h0 = fmaf(a.x, RR[4 * q + 0], h0);                                   \
      h1 = fmaf(a.y, RR[4 * q + 1], h1);                                   \
      h2 = fmaf(a.z, RR[4 * q + 2], h2);                                   \
      h3 = fmaf(a.w, RR[4 * q + 3], h3);                                   \
    }                                                                      \
    SLO = (i0 + i1) + (i2 + i3);                                           \
    SHI = (h0 + h1) + (h2 + h3);                                           \
  }

__global__ __launch_bounds__(512, 1) void semicrf(
    const float* __restrict__ seg, const float* __restrict__ tr,
    float* __restrict__ out, u64* axp, u64* acc) {
  const int b = blockIdx.x / BPB;
  const int role = blockIdx.x % BPB;
  const int tid = threadIdx.x;
  const int pair = tid >> 7;
  const int tp = tid & 127;
  const int wv = tp >> 6;
  const bool act = tp < Ln;
  const int ln = act ? tp : (Ln - 1);

  __shared__ __align__(16) float E[LSQ];             // exp(trans) 36 KB
  __shared__ __align__(16) float AlbR[8][Ln];        // finalizer alpha ring
  __shared__ float CRng[8][2];                       // per-wave-half C ring
  __shared__ __align__(16) float slotC[4][3][Ln];    // d=2..4 contributions
  __shared__ __align__(16) float Alb_s[RPB][2][Ln];  // relay staging (dbuf)
  __shared__ float CstS[RPB][2][2];                  // staged C halves
  __shared__ float redbuf[2];
  __shared__ int seqAw[2];
  __shared__ int sp[3][2];
  __shared__ int stg[RPB][2];
  __shared__ int rfl[2];

  if (tid < 2) { seqAw[tid] = -1; rfl[tid] = -1; }
  if (tid < 6) sp[tid >> 1][tid & 1] = -1;
  if (tid < RPB * 2) stg[tid >> 1][tid & 1] = -1;
  for (int i = tid; i < LSQ; i += 512) E[i] = __expf(tr[i]);
  __syncthreads();  // the only block-wide barrier

  if (role != 0) {
    // ==================== relay pair, offset d in [5..63] ===================
    const int d = DMIN + RPB * (role - 1) + pair;
    if (d > Wn) return;
    const int j = d & 7;
    u64* chain = acc + (size_t)(j * 4 + b) * Tn * Ln;
    const u64* axB = axp + (size_t)b * Tn * Ln;
    float R[Ln];
#pragma unroll
    for (int lp = 0; lp < Ln; ++lp) R[lp] = E[lp * Ln + ln];
    int wc = 1;
    const bool aHead = (d + KCH > Wn);

    float segq[PF];
#pragma unroll
    for (int K = 0; K < PF; ++K) segq[K] = seg[SIDX(b, K + 1, d + K) + ln];
    u64 upN = __hip_atomic_load(&axB[ln], RLX, AGENT);  // s=0
    u64 uaN = 0;

    for (int tb = d; tb < Tn; tb += PF) {
#pragma unroll
      for (int K = 0; K < PF; ++K) {
        const int t = tb + K;
        if (t >= Tn) continue;
        const int s = t - d;
        const int w = (t <= Wn) ? (s + 1) : (64 - d);
        if (w > wc) {
          wc = w;
#pragma unroll
          for (int lp = 0; lp < Ln; ++lp) R[lp] *= E[lp * Ln + ln];
        }
        const float segv = segq[K];
        if (t + PF < Tn) segq[K] = seg[SIDX(b, s + PF + 1, t + PF) + ln];
        u64 up = upN;
        if (t + 1 < Tn)
          upN = __hip_atomic_load(&axB[(size_t)(s + 1) * Ln + ln], RLX, AGENT);
        u64 ua = uaN;
        const bool head = aHead || (s < KCH);
        if (t + 1 < Tn && !(aHead || (s + 1 < KCH)))
          uaN = __hip_atomic_load(&chain[(size_t)(t + 1) * Ln + ln], RLX, AGENT);
        while ((u32)(up >> 32) == SENT)
          up = __hip_atomic_load(&axB[(size_t)s * Ln + ln], RLX, AGENT);
        const int buf = t & 1;
        if (act) Alb_s[pair][buf][tp] = __uint_as_float((u32)up);
        if (tp == 0 || tp == 64)
          CstS[pair][buf][tp >> 6] = __uint_as_float((u32)(up >> 32));
        if ((tp & 63) == 0) __hip_atomic_store(&stg[pair][wv], t, REL, WG);
        while (__hip_atomic_load(&stg[pair][wv ^ 1], ACQ, WG) < t) {}
        const float C0 = CstS[pair][buf][0], C1 = CstS[pair][buf][1];
        MATVEC(Alb_s[pair][buf], R, Slo, Shi)
        const float c = comb(Slo, Shi, C0, C1, (float)w * segv);
        float m, v;
        if (head) {
          m = c;
          v = 1.f;
        } else {
          while (((ua >> 32) & 0xFFu) != (u32)(d + KCH))
            ua = __hip_atomic_load(&chain[(size_t)t * Ln + ln], RLX, AGENT);
          const float pm = __uint_as_float((u32)ua);
          const float pv = __uint_as_float(((u32)(ua >> 32)) & ~0xFFu);
          const float nm = fmaxf(pm, c);
          v = pv * __expf(pm - nm) + __expf(c - nm);
          m = nm;
        }
        if (act) {
          const u32 vb = (__float_as_uint(v) & ~0xFFu) | (u32)d;
          __hip_atomic_store(&chain[(size_t)t * Ln + ln],
                             (u64)__float_as_uint(m) | ((u64)vb << 32), RLX,
                             AGENT);
        }
      }
    }
    return;
  }

  if (pair != 0) {
    // ============== in-block pair: offset d = pair+1 in {2,3,4} =============
    const int d = pair + 1;
    float R[Ln];
#pragma unroll
    for (int lp = 0; lp < Ln; ++lp) R[lp] = E[lp * Ln + ln];
    int wc = 1;
    float segq[PF];
#pragma unroll
    for (int K = 0; K < PF; ++K) segq[K] = seg[SIDX(b, K + 1, d + K) + ln];

    for (int tb = d; tb < Tn; tb += PF) {
#pragma unroll
      for (int K = 0; K < PF; ++K) {
        const int t = tb + K;
        if (t >= Tn) continue;
        const int s = t - d;
        const int w = (t <= Wn) ? (s + 1) : (64 - d);
        if (w > wc) {
          wc = w;
#pragma unroll
          for (int lp = 0; lp < Ln; ++lp) R[lp] *= E[lp * Ln + ln];
        }
        const float segv = segq[K];
        if (t + PF < Tn) segq[K] = seg[SIDX(b, s + PF + 1, t + PF) + ln];
        while (__hip_atomic_load(&seqAw[0], ACQ, WG) < s) {}
        while (__hip_atomic_load(&seqAw[1], ACQ, WG) < s) {}
        const float C0 = CRng[s & 7][0], C1 = CRng[s & 7][1];
        MATVEC(AlbR[s & 7], R, Slo, Shi)
        const float c = comb(Slo, Shi, C0, C1, (float)w * segv);
        if (act) slotC[t & 3][pair - 1][tp] = c;
        if ((tp & 63) == 0) __hip_atomic_store(&sp[pair - 1][wv], t, REL, WG);
      }
    }
    return;
  }

  // ================== pair 0: d=1 + global merge + publish ==================
  const float bos = tr[LSQ + ln];
  u64* axpB = axp + (size_t)b * Tn * Ln;
  float R1[Ln];
#pragma unroll
  for (int lp = 0; lp < Ln; ++lp) R1[lp] = E[lp * Ln + ln];
  int w1c = 1;

  {  // seed t=0: alpha0 = exp(seg[b,0,0,:]+bos) (reference stores exp'd value)
    const float a0 = __expf(seg[SIDX(b, 0, 0) + ln] + bos);
    const float Cw = wmaxred(act ? a0 : NEGINF);
    const float ax0 = __expf(a0 - Cw);
    if (act) AlbR[0][tp] = ax0;
    if ((tp & 63) == 0) {
      CRng[0][wv] = Cw;
      __hip_atomic_store(&seqAw[wv], 0, REL, WG);
    }
    if (act) __hip_atomic_store(&axpB[tp], pack2(ax0, Cw), RLX, AGENT);
  }

  float s1q[PF], szq[PF];
#pragma unroll
  for (int K = 0; K < PF; ++K) {
    s1q[K] = seg[SIDX(b, 1 + K, 1 + K) + ln];
    szq[K] = seg[SIDX(b, 0, 1 + K) + ln];
  }
  u64 ueN[8];
#pragma unroll
  for (int jj = 0; jj < 8; ++jj) ueN[jj] = 0;

  for (int tb = 1; tb < Tn; tb += PF) {
#pragma unroll
    for (int K = 0; K < PF; ++K) {
      const int t = tb + K;
      if (t >= Tn) continue;
      const int s = t - 1;
      const float s1 = s1q[K];
      const float szv = szq[K];
      if (t + PF < Tn) {
        s1q[K] = seg[SIDX(b, t + PF, t + PF) + ln];
        szq[K] = seg[SIDX(b, 0, t + PF) + ln];
      }
      u64 uu[8];
#pragma unroll
      for (int jj = 0; jj < 8; ++jj) {
        const int ed = (jj >= 5) ? jj : (jj + 8);
        uu[jj] = ueN[jj];
        if (t + 1 < Tn && t + 1 >= ed)
          ueN[jj] = __hip_atomic_load(
              &acc[((size_t)(jj * 4 + b) * Tn + (t + 1)) * Ln + ln], RLX,
              AGENT);
      }
      const int w1 = (t <= Wn) ? t : Wn;
      if (w1 > w1c) {
        w1c = w1;
#pragma unroll
        for (int lp = 0; lp < Ln; ++lp) R1[lp] *= E[lp * Ln + ln];
      }
      while (__hip_atomic_load(&seqAw[wv ^ 1], ACQ, WG) < s) {}
      const float C0 = CRng[s & 7][0], C1 = CRng[s & 7][1];
      MATVEC(AlbR[s & 7], R1, Slo, Shi)
      const float c1 = comb(Slo, Shi, C0, C1, (float)w1 * s1);
      float cc0 = NEGINF, cc1 = NEGINF, cc2 = NEGINF;
      if (t >= 2) {
        while (__hip_atomic_load(&sp[0][wv], ACQ, WG) < t) {}
        cc0 = slotC[t & 3][0][ln];
      }
      if (t >= 3) {
        while (__hip_atomic_load(&sp[1][wv], ACQ, WG) < t) {}
        cc1 = slotC[t & 3][1][ln];
      }
      if (t >= 4) {
        while (__hip_atomic_load(&sp[2][wv], ACQ, WG) < t) {}
        cc2 = slotC[t & 3][2][ln];
      }
      float em[8], ev[8];
#pragma unroll
      for (int jj = 0; jj < 8; ++jj) {
        const int ed = (jj >= 5) ? jj : (jj + 8);
        if (t >= ed) {
          u64 x = uu[jj];
          while (((x >> 32) & 0xFFu) != (u32)ed)
            x = __hip_atomic_load(
                &acc[((size_t)(jj * 4 + b) * Tn + t) * Ln + ln], RLX, AGENT);
          em[jj] = __uint_as_float((u32)x);
          ev[jj] = __uint_as_float(((u32)(x >> 32)) & ~0xFFu);
        } else {
          em[jj] = NEGINF;
          ev[jj] = 0.f;
        }
      }
      const float zv = (t <= Wn) ? (float)(t + 1) * (szv + bos) : NEGINF;
      float M = fmaxf(c1, zv);
      M = fmaxf(M, fmaxf(fmaxf(cc0, cc1), cc2));
#pragma unroll
      for (int jj = 0; jj < 8; ++jj) M = fmaxf(M, em[jj]);
      float vs = __expf(c1 - M) + __expf(zv - M);
      vs += __expf(cc0 - M) + __expf(cc1 - M) + __expf(cc2 - M);
#pragma unroll
      for (int jj = 0; jj < 8; ++jj) vs += ev[jj] * __expf(em[jj] - M);
      const float alpha = M + __logf(vs);

      const float Cw = wmaxred(act ? alpha : NEGINF);
      const float axn = __expf(alpha - Cw);
      if (act) AlbR[t & 7][tp] = axn;
      if ((tp & 63) == 0) {
        CRng[t & 7][wv] = Cw;
        __hip_atomic_store(&seqAw[wv], t, REL, WG);
      }
      if (act)
        __hip_atomic_store(&axpB[(size_t)t * Ln + tp], pack2(axn, Cw), RLX,
                           AGENT);
      if (t == Tn - 1) {
        const float sw = wsumred(act ? axn : 0.f);
        const float Gw = Cw + __logf(sw);
        if ((tp & 63) == 0) {
          redbuf[wv] = Gw;
          __hip_atomic_store(&rfl[wv], 1, REL, WG);
        }
        if (tid == 0) {
          while (__hip_atomic_load(&rfl[1], ACQ, WG) < 1) {}
          const float G0 = redbuf[0], G1 = redbuf[1];
          const float Mx = fmaxf(G0, G1);
          out[b] = Mx + __logf(__expf(G0 - Mx) + __expf(G1 - Mx));
        }
      }
    }
  }
}

extern "C" void kernel_launch(void* const* d_in, const int* in_sizes, int n_in,
                              void* d_out, int out_size, void* d_ws,
                              size_t ws_size, hipStream_t stream) {
  const float* seg = (const float*)d_in[0];  // (4,512,512,96) f32
  const float* tr = (const float*)d_in[1];   // (97,96) f32
  float* out = (float*)d_out;                // (4,) f32

  u64* axp = (u64*)d_ws;                 // [4][512][96]
  u64* acc = axp + (size_t)4 * Tn * Ln;  // [8][4][512][96]

  hipLaunchKernelGGL(init_ws, dim3(2048), dim3(256), 0, stream, (u64*)d_ws);
  hipLaunchKernelGGL(semicrf, dim3(4 * BPB), dim3(512), 0, stream, seg, tr,
                     out, axp, acc);
}

// Round 5
// 1346.435 us; speedup vs baseline: 1.7296x; 1.7296x over previous
//
#include <hip/hip_runtime.h>

// Semi-CRF log-partition. B=4, T=512, L=96, W=63.
// v5 = v3 topology (finalizer block: pair0=d1+merge+publish, pairs d=2,3,4 via
// LDS; relay pairs d=5..63 in 8 interleaved chains of depth<=8) + atomic diet:
//   - relays gate on a scalar per-batch step counter aseq[b] polled by ONE lane
//     per wave with s_sleep (was: wave-wide 512B polls -> MALL contention)
//   - s_sleep(1) in relay chain-merge spins (8-step slack)
//   - depth-1 rolling seg prefetch in the smallest-slack roles (d=1..4)
// All data handoffs remain single 8B relaxed agent atomics, self-validating
// (NaN sentinel in axp hi-word, chain tag in acc low mantissa bits).

#define Tn 512
#define Ln 96
#define LSQ (Ln * Ln)
#define Wn 63
#define KCH 8
#define DMIN 5
#define RPB 4
#define BPB 16
#define NEGINF (-1e30f)
#define SENT 0x7FC00000u

#define AGENT __HIP_MEMORY_SCOPE_AGENT
#define WG __HIP_MEMORY_SCOPE_WORKGROUP
#define RLX __ATOMIC_RELAXED
#define ACQ __ATOMIC_ACQUIRE
#define REL __ATOMIC_RELEASE

#define SIDX(b, i, t) ((((size_t)(b) * Tn + (i)) * Tn + (t)) * Ln)

typedef unsigned long long u64;
typedef unsigned int u32;

__device__ __forceinline__ float wmaxred(float v) {
#pragma unroll
  for (int m = 32; m >= 1; m >>= 1) v = fmaxf(v, __shfl_xor(v, m, 64));
  return v;
}
__device__ __forceinline__ float wsumred(float v) {
#pragma unroll
  for (int m = 32; m >= 1; m >>= 1) v += __shfl_xor(v, m, 64);
  return v;
}
__device__ __forceinline__ u64 pack2(float lo, float hi) {
  return (u64)__float_as_uint(lo) | ((u64)__float_as_uint(hi) << 32);
}

__global__ void init_ws(u64* ws, int* aseq) {
  const size_t n1 = (size_t)4 * Tn * Ln;
  const size_t n = n1 * (1 + KCH);
  for (size_t i = (size_t)blockIdx.x * blockDim.x + threadIdx.x; i < n;
       i += (size_t)gridDim.x * blockDim.x)
    ws[i] = (i < n1) ? (((u64)SENT) << 32) : 0ull;
  if (blockIdx.x == 0 && threadIdx.x < 4) aseq[threadIdx.x] = -1;
}

__global__ __launch_bounds__(512, 1) void semicrf(
    const float* __restrict__ seg, const float* __restrict__ tr,
    float* __restrict__ out, u64* axp, u64* acc, int* aseq) {
  const int b = blockIdx.x / BPB;
  const int role = blockIdx.x % BPB;
  const int tid = threadIdx.x;
  const int pair = tid >> 7;
  const int tp = tid & 127;
  const int wv = tp >> 6;
  const bool act = tp < Ln;
  const int ln = act ? tp : (Ln - 1);

  __shared__ __align__(16) float E[LSQ];             // exp(trans) 36 KB
  __shared__ __align__(16) float AlbR[8][Ln];        // finalizer alpha ring
  __shared__ float CRng[8];                          // finalizer C ring
  __shared__ __align__(16) float slotC[4][3][Ln];    // d=2..4 contributions
  __shared__ __align__(16) float Alb_s[RPB][2][Ln];  // relay staging (dbuf)
  __shared__ float redbuf[2][2];                     // [t&1][wv]
  __shared__ int seqAw[2];
  __shared__ int sp[3][2];
  __shared__ int stg[RPB][2];
  __shared__ int rfl[2];

  if (tid < 2) { seqAw[tid] = -1; rfl[tid] = -1; }
  if (tid < 6) sp[tid >> 1][tid & 1] = -1;
  if (tid < RPB * 2) stg[tid >> 1][tid & 1] = -1;
  for (int i = tid; i < LSQ; i += 512) E[i] = __expf(tr[i]);
  __syncthreads();  // the only block-wide barrier

  if (role != 0) {
    // ==================== relay pair, offset d in [5..63] ===================
    const int d = DMIN + RPB * (role - 1) + pair;
    if (d > Wn) return;
    const int j = d & 7;
    u64* chain = acc + (size_t)(j * 4 + b) * Tn * Ln;
    const u64* axB = axp + (size_t)b * Tn * Ln;
    float R[Ln];
#pragma unroll
    for (int lp = 0; lp < Ln; ++lp) R[lp] = E[lp * Ln + ln];
    int wc = 1;
    const bool aHead = (d + KCH > Wn);

    for (int t = d; t < Tn; ++t) {
      const int s = t - d;
      const int w = (t <= Wn) ? (s + 1) : (64 - d);
      if (w > wc) {
        wc = w;
#pragma unroll
        for (int lp = 0; lp < Ln; ++lp) R[lp] *= E[lp * Ln + ln];
      }
      const float segv = seg[SIDX(b, s + 1, t) + ln];  // hidden under gate
      const size_t tIdx = (size_t)t * Ln + ln;
      const bool head = aHead || (s < KCH);
      u64 ua = 0;
      if (!head) ua = __hip_atomic_load(&chain[tIdx], RLX, AGENT);  // early

      // gate on scalar step counter (1 lane per wave), then wave data load
      int hint = __shfl(
          ((tp & 63) == 0) ? __hip_atomic_load(&aseq[b], RLX, AGENT) : 0, 0,
          64);
      while (hint < s) {
        __builtin_amdgcn_s_sleep(1);
        hint = __shfl(
            ((tp & 63) == 0) ? __hip_atomic_load(&aseq[b], RLX, AGENT) : 0, 0,
            64);
      }
      u64 up = __hip_atomic_load(&axB[(size_t)s * Ln + ln], RLX, AGENT);
      while ((u32)(up >> 32) == SENT)  // rare: per-lane self-validation
        up = __hip_atomic_load(&axB[(size_t)s * Ln + ln], RLX, AGENT);

      const int buf = t & 1;
      if (act) Alb_s[pair][buf][tp] = __uint_as_float((u32)up);
      const float Cs = __uint_as_float((u32)(up >> 32));
      __hip_atomic_store(&stg[pair][wv], t, REL, WG);
      while (__hip_atomic_load(&stg[pair][wv ^ 1], ACQ, WG) < t) {}

      float i0 = 0, i1 = 0, i2 = 0, i3 = 0;
      const float4* A4 = (const float4*)Alb_s[pair][buf];
#pragma unroll
      for (int q = 0; q < 24; ++q) {
        float4 a = A4[q];
        i0 = fmaf(a.x, R[4 * q + 0], i0);
        i1 = fmaf(a.y, R[4 * q + 1], i1);
        i2 = fmaf(a.z, R[4 * q + 2], i2);
        i3 = fmaf(a.w, R[4 * q + 3], i3);
      }
      const float c = Cs + (float)w * segv + __logf((i0 + i1) + (i2 + i3));

      float m, v;
      if (head) {
        m = c;
        v = 1.f;
      } else {
        while (((ua >> 32) & 0xFFu) != (u32)(d + KCH)) {
          __builtin_amdgcn_s_sleep(1);  // 8-step slack
          ua = __hip_atomic_load(&chain[tIdx], RLX, AGENT);
        }
        const float pm = __uint_as_float((u32)ua);
        const float pv = __uint_as_float(((u32)(ua >> 32)) & ~0xFFu);
        const float nm = fmaxf(pm, c);
        v = pv * __expf(pm - nm) + __expf(c - nm);
        m = nm;
      }
      if (act) {
        const u32 vb = (__float_as_uint(v) & ~0xFFu) | (u32)d;
        __hip_atomic_store(&chain[tIdx],
                           (u64)__float_as_uint(m) | ((u64)vb << 32), RLX,
                           AGENT);
      }
    }
    return;
  }

  if (pair != 0) {
    // ============== in-block pair: offset d = pair+1 in {2,3,4} =============
    const int d = pair + 1;
    float R[Ln];
#pragma unroll
    for (int lp = 0; lp < Ln; ++lp) R[lp] = E[lp * Ln + ln];
    int wc = 1;
    float segn = seg[SIDX(b, 1, d) + ln];  // t=d: row s+1=1
    for (int t = d; t < Tn; ++t) {
      const int s = t - d;
      const int w = (t <= Wn) ? (s + 1) : (64 - d);
      const float segv = segn;
      if (t + 1 < Tn) segn = seg[SIDX(b, s + 2, t + 1) + ln];  // depth-1 PF
      if (w > wc) {
        wc = w;
#pragma unroll
        for (int lp = 0; lp < Ln; ++lp) R[lp] *= E[lp * Ln + ln];
      }
      while (__hip_atomic_load(&seqAw[0], ACQ, WG) < s) {}
      while (__hip_atomic_load(&seqAw[1], ACQ, WG) < s) {}
      const float Cs = CRng[s & 7];
      float i0 = 0, i1 = 0, i2 = 0, i3 = 0;
      const float4* A4 = (const float4*)AlbR[s & 7];
#pragma unroll
      for (int q = 0; q < 24; ++q) {
        float4 a = A4[q];
        i0 = fmaf(a.x, R[4 * q + 0], i0);
        i1 = fmaf(a.y, R[4 * q + 1], i1);
        i2 = fmaf(a.z, R[4 * q + 2], i2);
        i3 = fmaf(a.w, R[4 * q + 3], i3);
      }
      const float c = Cs + (float)w * segv + __logf((i0 + i1) + (i2 + i3));
      if (act) slotC[t & 3][pair - 1][tp] = c;
      __hip_atomic_store(&sp[pair - 1][wv], t, REL, WG);
    }
    return;
  }

  // ================== pair 0: d=1 + global merge + publish ==================
  const float bos = tr[LSQ + ln];
  u64* axpB = axp + (size_t)b * Tn * Ln;
  float R1[Ln];
#pragma unroll
  for (int lp = 0; lp < Ln; ++lp) R1[lp] = E[lp * Ln + ln];
  int w1c = 1;
  const int endd[8] = {8, 9, 10, 11, 12, 5, 6, 7};  // chain end per residue

  {  // seed t=0: alpha0 = exp(seg[b,0,0,:]+bos) (reference stores exp'd value)
    const float a0 = __expf(seg[SIDX(b, 0, 0) + ln] + bos);
    const float wm = wmaxred(act ? a0 : NEGINF);
    if ((tp & 63) == 0) redbuf[0][wv] = wm;
    __hip_atomic_store(&rfl[wv], 0, REL, WG);
    while (__hip_atomic_load(&rfl[wv ^ 1], ACQ, WG) < 0) {}
    const float C0 = fmaxf(redbuf[0][0], redbuf[0][1]);
    const float ax0 = __expf(a0 - C0);
    if (act) AlbR[0][tp] = ax0;
    if (tid == 0) CRng[0] = C0;
    __hip_atomic_store(&seqAw[wv], 0, REL, WG);
    if (act)
      __hip_atomic_store(&axpB[tp], pack2(ax0, C0), RLX, AGENT);
    if (tid == 0) __hip_atomic_store(&aseq[b], 0, RLX, AGENT);
  }

  float s1n = seg[SIDX(b, 1, 1) + ln];
  float szn = seg[SIDX(b, 0, 1) + ln];

  for (int t = 1; t < Tn; ++t) {
    const int s = t - 1;
    // early loads for this step
    u64 u[8];
#pragma unroll
    for (int jj = 0; jj < 8; ++jj)
      if (t >= endd[jj])
        u[jj] = __hip_atomic_load(
            &acc[(((size_t)jj * 4 + b) * Tn + t) * Ln + ln], RLX, AGENT);
    const float s1 = s1n;
    const float szv = szn;
    if (t + 1 < Tn) {  // depth-1 rolling prefetch
      s1n = seg[SIDX(b, t + 1, t + 1) + ln];
      szn = seg[SIDX(b, 0, t + 1) + ln];
    }

    const int w1 = (t <= Wn) ? t : Wn;
    if (w1 > w1c) {
      w1c = w1;
#pragma unroll
      for (int lp = 0; lp < Ln; ++lp) R1[lp] *= E[lp * Ln + ln];
    }
    float i0 = 0, i1 = 0, i2 = 0, i3 = 0;
    const float4* A4 = (const float4*)AlbR[s & 7];
#pragma unroll
    for (int q = 0; q < 24; ++q) {
      float4 a = A4[q];
      i0 = fmaf(a.x, R1[4 * q + 0], i0);
      i1 = fmaf(a.y, R1[4 * q + 1], i1);
      i2 = fmaf(a.z, R1[4 * q + 2], i2);
      i3 = fmaf(a.w, R1[4 * q + 3], i3);
    }
    const float c1 =
        CRng[s & 7] + (float)w1 * s1 + __logf((i0 + i1) + (i2 + i3));

    // in-block contributions d=2,3,4
    float cc[3];
#pragma unroll
    for (int k = 1; k <= 3; ++k) {
      if (t >= k + 1) {
        while (__hip_atomic_load(&sp[k - 1][wv], ACQ, WG) < t) {}
        cc[k - 1] = slotC[t & 3][k - 1][ln];
      } else
        cc[k - 1] = NEGINF;
    }
    // external chain ends
    float em[8], ev[8];
#pragma unroll
    for (int jj = 0; jj < 8; ++jj) {
      if (t >= endd[jj]) {
        const size_t aIdx = (((size_t)jj * 4 + b) * Tn + t) * Ln + ln;
        while (((u[jj] >> 32) & 0xFFu) != (u32)endd[jj])
          u[jj] = __hip_atomic_load(&acc[aIdx], RLX, AGENT);
        em[jj] = __uint_as_float((u32)u[jj]);
        ev[jj] = __uint_as_float(((u32)(u[jj] >> 32)) & ~0xFFu);
      } else {
        em[jj] = NEGINF;
        ev[jj] = 0.f;
      }
    }
    const float zv = (t <= Wn) ? (float)(t + 1) * (szv + bos) : NEGINF;

    // single-max LSE merge of {c1, cc[0..2], (em,ev)[0..7], zv}
    float M = c1;
#pragma unroll
    for (int k = 0; k < 3; ++k) M = fmaxf(M, cc[k]);
#pragma unroll
    for (int jj = 0; jj < 8; ++jj) M = fmaxf(M, em[jj]);
    M = fmaxf(M, zv);
    float vs = __expf(c1 - M) + __expf(zv - M);
#pragma unroll
    for (int k = 0; k < 3; ++k) vs += __expf(cc[k] - M);
#pragma unroll
    for (int jj = 0; jj < 8; ++jj) vs += ev[jj] * __expf(em[jj] - M);
    const float alpha = M + __logf(vs);

    // block-wide C = max(alpha) over 96 (pair0's two waves)
    const float wm = wmaxred(act ? alpha : NEGINF);
    if ((tp & 63) == 0) redbuf[t & 1][wv] = wm;
    __hip_atomic_store(&rfl[wv], t, REL, WG);
    while (__hip_atomic_load(&rfl[wv ^ 1], ACQ, WG) < t) {}
    const float C = fmaxf(redbuf[t & 1][0], redbuf[t & 1][1]);
    const float axn = __expf(alpha - C);
    if (act) AlbR[t & 7][tp] = axn;
    if (tid == 0) CRng[t & 7] = C;
    __hip_atomic_store(&seqAw[wv], t, REL, WG);
    if (act)
      __hip_atomic_store(&axpB[(size_t)t * Ln + tp], pack2(axn, C), RLX,
                         AGENT);
    if (tid == 0) __hip_atomic_store(&aseq[b], t, RLX, AGENT);

    if (t == Tn - 1) {
      const float sm = wsumred(act ? axn : 0.f);
      if ((tp & 63) == 0) redbuf[(t + 1) & 1][wv] = sm;
      __hip_atomic_store(&rfl[wv], t + 1, REL, WG);
      while (__hip_atomic_load(&rfl[wv ^ 1], ACQ, WG) < t + 1) {}
      if (tid == 0)
        out[b] = C + __logf(redbuf[(t + 1) & 1][0] + redbuf[(t + 1) & 1][1]);
    }
  }
}

extern "C" void kernel_launch(void* const* d_in, const int* in_sizes, int n_in,
                              void* d_out, int out_size, void* d_ws,
                              size_t ws_size, hipStream_t stream) {
  const float* seg = (const float*)d_in[0];  // (4,512,512,96) f32
  const float* tr = (const float*)d_in[1];   // (97,96) f32
  float* out = (float*)d_out;                // (4,) f32

  u64* axp = (u64*)d_ws;                 // [4][512][96]
  u64* acc = axp + (size_t)4 * Tn * Ln;  // [8][4][512][96]
  int* aseq = (int*)(acc + (size_t)8 * 4 * Tn * Ln);  // [4]

  hipLaunchKernelGGL(init_ws, dim3(2048), dim3(256), 0, stream, (u64*)d_ws,
                     aseq);
  hipLaunchKernelGGL(semicrf, dim3(4 * BPB), dim3(512), 0, stream, seg, tr,
                     out, axp, acc, aseq);
}

// Round 6
// 1328.231 us; speedup vs baseline: 1.7533x; 1.0137x over previous
//
#include <hip/hip_runtime.h>

// Semi-CRF log-partition. B=4, T=512, L=96, W=63.
// v6 = v3 topology with relay de-contention + latency pipelining:
//   - finalizer block (512 thr): pair0 = d1+merge+publish, pairs d=2,3,4 via LDS
//   - relay pairs d=5..63, ONE pair per block (128 active thr) -> ~1 CU each,
//     8 interleaved chains (residue d mod 8), depth <= 8
//   - relay gate: depth-1 prefetched alpha load (tight reload spin fallback)
//   - depth-1 rolling seg prefetch everywhere (register rotation, no unroll)
// All cross-block handoffs: single 8B relaxed agent atomics, self-validating
// (NaN sentinel in axp hi-word / chain tag in acc low mantissa bits of v).

#define Tn 512
#define Ln 96
#define LSQ (Ln * Ln)
#define Wn 63
#define KCH 8
#define NB 60  // blocks per batch: 1 finalizer + 59 relays (d=5..63)
#define NEGINF (-1e30f)
#define SENT 0x7FC00000u

#define AGENT __HIP_MEMORY_SCOPE_AGENT
#define WG __HIP_MEMORY_SCOPE_WORKGROUP
#define RLX __ATOMIC_RELAXED
#define ACQ __ATOMIC_ACQUIRE
#define REL __ATOMIC_RELEASE

#define SIDX(b, i, t) ((((size_t)(b) * Tn + (i)) * Tn + (t)) * Ln)

typedef unsigned long long u64;
typedef unsigned int u32;

__device__ __forceinline__ float wmaxred(float v) {
#pragma unroll
  for (int m = 32; m >= 1; m >>= 1) v = fmaxf(v, __shfl_xor(v, m, 64));
  return v;
}
__device__ __forceinline__ float wsumred(float v) {
#pragma unroll
  for (int m = 32; m >= 1; m >>= 1) v += __shfl_xor(v, m, 64);
  return v;
}
__device__ __forceinline__ u64 pack2(float lo, float hi) {
  return (u64)__float_as_uint(lo) | ((u64)__float_as_uint(hi) << 32);
}

__global__ void init_ws(u64* ws) {
  const size_t n1 = (size_t)4 * Tn * Ln;
  const size_t n = n1 * (1 + KCH);
  for (size_t i = (size_t)blockIdx.x * blockDim.x + threadIdx.x; i < n;
       i += (size_t)gridDim.x * blockDim.x)
    ws[i] = (i < n1) ? (((u64)SENT) << 32) : 0ull;
}

__global__ __launch_bounds__(512, 1) void semicrf(
    const float* __restrict__ seg, const float* __restrict__ tr,
    float* __restrict__ out, u64* axp, u64* acc) {
  const int b = blockIdx.x / NB;
  const int role = blockIdx.x % NB;
  const int tid = threadIdx.x;
  const int pair = tid >> 7;
  const int tp = tid & 127;
  const int wv = tp >> 6;
  const bool act = tp < Ln;
  const int ln = act ? tp : (Ln - 1);

  __shared__ __align__(16) float E[LSQ];           // exp(trans) 36 KB
  __shared__ __align__(16) float AlbR[8][Ln];      // finalizer alpha ring
  __shared__ float CRng[8];                        // finalizer C ring
  __shared__ __align__(16) float slotC[4][3][Ln];  // d=2..4 contributions
  __shared__ __align__(16) float Alb_s[2][Ln];     // relay staging (dbuf)
  __shared__ float redbuf[2][2];                   // [t&1][wv]
  __shared__ int seqAw[2];
  __shared__ int sp[3][2];
  __shared__ int stg[2];
  __shared__ int rfl[2];

  if (tid < 2) { seqAw[tid] = -1; rfl[tid] = -1; stg[tid] = -1; }
  if (tid < 6) sp[tid >> 1][tid & 1] = -1;
  for (int i = tid; i < LSQ; i += 512) E[i] = __expf(tr[i]);
  __syncthreads();  // the only block-wide barrier (all 512 present)

  if (role != 0) {
    // ============ relay pair, one per block, offset d in [5..63] ============
    if (tid >= 128) return;  // after the barrier: safe
    const int d = role + 4;
    const int j = d & 7;
    u64* chain = acc + (size_t)(j * 4 + b) * Tn * Ln;
    const u64* axB = axp + (size_t)b * Tn * Ln;
    float R[Ln];
#pragma unroll
    for (int lp = 0; lp < Ln; ++lp) R[lp] = E[lp * Ln + ln];
    int wc = 1;
    const bool aHead = (d + KCH > Wn);

    float segn = seg[SIDX(b, 1, d) + ln];                  // s=0 row
    u64 up = __hip_atomic_load(&axB[ln], RLX, AGENT);      // alpha[0] prefetch

    for (int t = d; t < Tn; ++t) {
      const int s = t - d;
      const int w = (t <= Wn) ? (s + 1) : (64 - d);
      if (w > wc) {
        wc = w;
#pragma unroll
        for (int lp = 0; lp < Ln; ++lp) R[lp] *= E[lp * Ln + ln];
      }
      const float segv = segn;
      if (t + 1 < Tn) segn = seg[SIDX(b, s + 2, t + 1) + ln];  // depth-1 PF
      const size_t tIdx = (size_t)t * Ln + ln;
      const bool head = aHead || (s < KCH);
      u64 ua = 0;
      if (!head) ua = __hip_atomic_load(&chain[tIdx], RLX, AGENT);  // early

      // gate: prefetched alpha[s]; tight reload spin only if not yet visible
      while ((u32)(up >> 32) == SENT)
        up = __hip_atomic_load(&axB[(size_t)s * Ln + ln], RLX, AGENT);
      const int buf = t & 1;
      if (act) Alb_s[buf][tp] = __uint_as_float((u32)up);
      const float Cs = __uint_as_float((u32)(up >> 32));
      __hip_atomic_store(&stg[wv], t, REL, WG);
      // prefetch next gate data while this step's compute runs
      if (t + 1 < Tn)
        up = __hip_atomic_load(&axB[(size_t)(s + 1) * Ln + ln], RLX, AGENT);
      while (__hip_atomic_load(&stg[wv ^ 1], ACQ, WG) < t) {}

      float i0 = 0, i1 = 0, i2 = 0, i3 = 0;
      const float4* A4 = (const float4*)Alb_s[buf];
#pragma unroll
      for (int q = 0; q < 24; ++q) {
        float4 a = A4[q];
        i0 = fmaf(a.x, R[4 * q + 0], i0);
        i1 = fmaf(a.y, R[4 * q + 1], i1);
        i2 = fmaf(a.z, R[4 * q + 2], i2);
        i3 = fmaf(a.w, R[4 * q + 3], i3);
      }
      const float c = Cs + (float)w * segv + __logf((i0 + i1) + (i2 + i3));

      float m, v;
      if (head) {
        m = c;
        v = 1.f;
      } else {
        while (((ua >> 32) & 0xFFu) != (u32)(d + KCH))
          ua = __hip_atomic_load(&chain[tIdx], RLX, AGENT);
        const float pm = __uint_as_float((u32)ua);
        const float pv = __uint_as_float(((u32)(ua >> 32)) & ~0xFFu);
        const float nm = fmaxf(pm, c);
        v = pv * __expf(pm - nm) + __expf(c - nm);
        m = nm;
      }
      if (act) {
        const u32 vb = (__float_as_uint(v) & ~0xFFu) | (u32)d;
        __hip_atomic_store(&chain[tIdx],
                           (u64)__float_as_uint(m) | ((u64)vb << 32), RLX,
                           AGENT);
      }
    }
    return;
  }

  if (pair != 0) {
    // ============== in-block pair: offset d = pair+1 in {2,3,4} =============
    const int d = pair + 1;
    float R[Ln];
#pragma unroll
    for (int lp = 0; lp < Ln; ++lp) R[lp] = E[lp * Ln + ln];
    int wc = 1;
    float segn = seg[SIDX(b, 1, d) + ln];
    for (int t = d; t < Tn; ++t) {
      const int s = t - d;
      const int w = (t <= Wn) ? (s + 1) : (64 - d);
      const float segv = segn;
      if (t + 1 < Tn) segn = seg[SIDX(b, s + 2, t + 1) + ln];  // depth-1 PF
      if (w > wc) {
        wc = w;
#pragma unroll
        for (int lp = 0; lp < Ln; ++lp) R[lp] *= E[lp * Ln + ln];
      }
      while (__hip_atomic_load(&seqAw[0], ACQ, WG) < s) {}
      while (__hip_atomic_load(&seqAw[1], ACQ, WG) < s) {}
      const float Cs = CRng[s & 7];
      float i0 = 0, i1 = 0, i2 = 0, i3 = 0;
      const float4* A4 = (const float4*)AlbR[s & 7];
#pragma unroll
      for (int q = 0; q < 24; ++q) {
        float4 a = A4[q];
        i0 = fmaf(a.x, R[4 * q + 0], i0);
        i1 = fmaf(a.y, R[4 * q + 1], i1);
        i2 = fmaf(a.z, R[4 * q + 2], i2);
        i3 = fmaf(a.w, R[4 * q + 3], i3);
      }
      const float c = Cs + (float)w * segv + __logf((i0 + i1) + (i2 + i3));
      if (act) slotC[t & 3][pair - 1][tp] = c;
      __hip_atomic_store(&sp[pair - 1][wv], t, REL, WG);
    }
    return;
  }

  // ================== pair 0: d=1 + global merge + publish ==================
  const float bos = tr[LSQ + ln];
  u64* axpB = axp + (size_t)b * Tn * Ln;
  float R1[Ln];
#pragma unroll
  for (int lp = 0; lp < Ln; ++lp) R1[lp] = E[lp * Ln + ln];
  int w1c = 1;
  const int endd[8] = {8, 9, 10, 11, 12, 5, 6, 7};  // chain end per residue

  {  // seed t=0: alpha0 = exp(seg[b,0,0,:]+bos) (reference stores exp'd value)
    const float a0 = __expf(seg[SIDX(b, 0, 0) + ln] + bos);
    const float wm = wmaxred(act ? a0 : NEGINF);
    if ((tp & 63) == 0) redbuf[0][wv] = wm;
    __hip_atomic_store(&rfl[wv], 0, REL, WG);
    while (__hip_atomic_load(&rfl[wv ^ 1], ACQ, WG) < 0) {}
    const float C0 = fmaxf(redbuf[0][0], redbuf[0][1]);
    const float ax0 = __expf(a0 - C0);
    if (act) AlbR[0][tp] = ax0;
    if (tid == 0) CRng[0] = C0;
    __hip_atomic_store(&seqAw[wv], 0, REL, WG);
    if (act) __hip_atomic_store(&axpB[tp], pack2(ax0, C0), RLX, AGENT);
  }

  float s1n = seg[SIDX(b, 1, 1) + ln];
  float szn = seg[SIDX(b, 0, 1) + ln];

  for (int t = 1; t < Tn; ++t) {
    const int s = t - 1;
    // early loads for this step (8 independent MALL reads overlap)
    u64 u[8];
#pragma unroll
    for (int jj = 0; jj < 8; ++jj)
      if (t >= endd[jj])
        u[jj] = __hip_atomic_load(
            &acc[(((size_t)jj * 4 + b) * Tn + t) * Ln + ln], RLX, AGENT);
    const float s1 = s1n;
    const float szv = szn;
    if (t + 1 < Tn) {  // depth-1 rolling prefetch
      s1n = seg[SIDX(b, t + 1, t + 1) + ln];
      szn = seg[SIDX(b, 0, t + 1) + ln];
    }

    const int w1 = (t <= Wn) ? t : Wn;
    if (w1 > w1c) {
      w1c = w1;
#pragma unroll
      for (int lp = 0; lp < Ln; ++lp) R1[lp] *= E[lp * Ln + ln];
    }
    float i0 = 0, i1 = 0, i2 = 0, i3 = 0;
    const float4* A4 = (const float4*)AlbR[s & 7];
#pragma unroll
    for (int q = 0; q < 24; ++q) {
      float4 a = A4[q];
      i0 = fmaf(a.x, R1[4 * q + 0], i0);
      i1 = fmaf(a.y, R1[4 * q + 1], i1);
      i2 = fmaf(a.z, R1[4 * q + 2], i2);
      i3 = fmaf(a.w, R1[4 * q + 3], i3);
    }
    const float c1 =
        CRng[s & 7] + (float)w1 * s1 + __logf((i0 + i1) + (i2 + i3));

    // in-block contributions d=2,3,4
    float cc[3];
#pragma unroll
    for (int k = 1; k <= 3; ++k) {
      if (t >= k + 1) {
        while (__hip_atomic_load(&sp[k - 1][wv], ACQ, WG) < t) {}
        cc[k - 1] = slotC[t & 3][k - 1][ln];
      } else
        cc[k - 1] = NEGINF;
    }
    // external chain ends
    float em[8], ev[8];
#pragma unroll
    for (int jj = 0; jj < 8; ++jj) {
      if (t >= endd[jj]) {
        const size_t aIdx = (((size_t)jj * 4 + b) * Tn + t) * Ln + ln;
        while (((u[jj] >> 32) & 0xFFu) != (u32)endd[jj])
          u[jj] = __hip_atomic_load(&acc[aIdx], RLX, AGENT);
        em[jj] = __uint_as_float((u32)u[jj]);
        ev[jj] = __uint_as_float(((u32)(u[jj] >> 32)) & ~0xFFu);
      } else {
        em[jj] = NEGINF;
        ev[jj] = 0.f;
      }
    }
    const float zv = (t <= Wn) ? (float)(t + 1) * (szv + bos) : NEGINF;

    // single-max LSE merge of {c1, cc[0..2], (em,ev)[0..7], zv}
    float M = c1;
#pragma unroll
    for (int k = 0; k < 3; ++k) M = fmaxf(M, cc[k]);
#pragma unroll
    for (int jj = 0; jj < 8; ++jj) M = fmaxf(M, em[jj]);
    M = fmaxf(M, zv);
    float vs = __expf(c1 - M) + __expf(zv - M);
#pragma unroll
    for (int k = 0; k < 3; ++k) vs += __expf(cc[k] - M);
#pragma unroll
    for (int jj = 0; jj < 8; ++jj) vs += ev[jj] * __expf(em[jj] - M);
    const float alpha = M + __logf(vs);

    // block-wide C = max(alpha) over 96 (pair0's two waves)
    const float wm = wmaxred(act ? alpha : NEGINF);
    if ((tp & 63) == 0) redbuf[t & 1][wv] = wm;
    __hip_atomic_store(&rfl[wv], t, REL, WG);
    while (__hip_atomic_load(&rfl[wv ^ 1], ACQ, WG) < t) {}
    const float C = fmaxf(redbuf[t & 1][0], redbuf[t & 1][1]);
    const float axn = __expf(alpha - C);
    if (act) AlbR[t & 7][tp] = axn;
    if (tid == 0) CRng[t & 7] = C;
    __hip_atomic_store(&seqAw[wv], t, REL, WG);
    if (act)
      __hip_atomic_store(&axpB[(size_t)t * Ln + tp], pack2(axn, C), RLX,
                         AGENT);

    if (t == Tn - 1) {
      const float sm = wsumred(act ? axn : 0.f);
      if ((tp & 63) == 0) redbuf[(t + 1) & 1][wv] = sm;
      __hip_atomic_store(&rfl[wv], t + 1, REL, WG);
      while (__hip_atomic_load(&rfl[wv ^ 1], ACQ, WG) < t + 1) {}
      if (tid == 0)
        out[b] = C + __logf(redbuf[(t + 1) & 1][0] + redbuf[(t + 1) & 1][1]);
    }
  }
}

extern "C" void kernel_launch(void* const* d_in, const int* in_sizes, int n_in,
                              void* d_out, int out_size, void* d_ws,
                              size_t ws_size, hipStream_t stream) {
  const float* seg = (const float*)d_in[0];  // (4,512,512,96) f32
  const float* tr = (const float*)d_in[1];   // (97,96) f32
  float* out = (float*)d_out;                // (4,) f32

  u64* axp = (u64*)d_ws;                 // [4][512][96]
  u64* acc = axp + (size_t)4 * Tn * Ln;  // [8][4][512][96]

  hipLaunchKernelGGL(init_ws, dim3(2048), dim3(256), 0, stream, (u64*)d_ws);
  hipLaunchKernelGGL(semicrf, dim3(4 * NB), dim3(512), 0, stream, seg, tr,
                     out, axp, acc);
}

// Round 7
// 1090.656 us; speedup vs baseline: 2.1352x; 1.2178x over previous
//
#include <hip/hip_runtime.h>

// Semi-CRF log-partition. B=4, T=512, L=96, W=63.
// v7 = v3 topology, with ALL workgroup-scope acquire/release flag sync replaced
// by relaxed LDS atomics + explicit s_waitcnt lgkmcnt(0).
// WHY: WG-scope release stores compile to s_waitcnt vmcnt(0) lgkmcnt(0) + store,
// draining every in-flight global load/store (HBM seg loads ~1us, MALL chain
// loads ~0.7us) once or twice PER STEP in every role. That drain was the flat
// ~2us/step across v2-v6. LDS-only ordering (lgkmcnt) is correct for flags
// guarding LDS-staged data within one CU, and costs ~30 cycles instead.
// Cross-block handoffs stay single 8B relaxed agent atomics, self-validating
// (NaN sentinel in axp hi-word; chain tag in acc low mantissa bits of v).

#define Tn 512
#define Ln 96
#define LSQ (Ln * Ln)
#define Wn 63
#define KCH 8
#define DMIN 5
#define RPB 4
#define BPB 16
#define NEGINF (-1e30f)
#define SENT 0x7FC00000u

#define AGENT __HIP_MEMORY_SCOPE_AGENT
#define WG __HIP_MEMORY_SCOPE_WORKGROUP
#define RLX __ATOMIC_RELAXED

// LDS producer fence: prior ds_writes completed before the next (flag) write.
#define LDSF() asm volatile("s_waitcnt lgkmcnt(0)" ::: "memory")
// Compiler-only barrier after a relaxed spin: forbid hoisting data reads.
#define CBAR() asm volatile("" ::: "memory")

#define SIDX(b, i, t) ((((size_t)(b) * Tn + (i)) * Tn + (t)) * Ln)

typedef unsigned long long u64;
typedef unsigned int u32;

__device__ __forceinline__ float wmaxred(float v) {
#pragma unroll
  for (int m = 32; m >= 1; m >>= 1) v = fmaxf(v, __shfl_xor(v, m, 64));
  return v;
}
__device__ __forceinline__ float wsumred(float v) {
#pragma unroll
  for (int m = 32; m >= 1; m >>= 1) v += __shfl_xor(v, m, 64);
  return v;
}
__device__ __forceinline__ u64 pack2(float lo, float hi) {
  return (u64)__float_as_uint(lo) | ((u64)__float_as_uint(hi) << 32);
}

__global__ void init_ws(u64* ws) {
  const size_t n1 = (size_t)4 * Tn * Ln;
  const size_t n = n1 * (1 + KCH);
  for (size_t i = (size_t)blockIdx.x * blockDim.x + threadIdx.x; i < n;
       i += (size_t)gridDim.x * blockDim.x)
    ws[i] = (i < n1) ? (((u64)SENT) << 32) : 0ull;
}

__global__ __launch_bounds__(512, 1) void semicrf(
    const float* __restrict__ seg, const float* __restrict__ tr,
    float* __restrict__ out, u64* axp, u64* acc) {
  const int b = blockIdx.x / BPB;
  const int role = blockIdx.x % BPB;
  const int tid = threadIdx.x;
  const int pair = tid >> 7;
  const int tp = tid & 127;
  const int wv = tp >> 6;
  const bool act = tp < Ln;
  const int ln = act ? tp : (Ln - 1);

  __shared__ __align__(16) float E[LSQ];             // exp(trans) 36 KB
  __shared__ __align__(16) float AlbR[8][Ln];        // finalizer alpha ring
  __shared__ float CRng[8];                          // finalizer C ring
  __shared__ __align__(16) float slotC[4][3][Ln];    // d=2..4 contributions
  __shared__ __align__(16) float Alb_s[RPB][2][Ln];  // relay staging (dbuf)
  __shared__ float redbuf[2][2];                     // [t&1][wv]
  __shared__ int seqAw[2];
  __shared__ int sp[3][2];
  __shared__ int stg[RPB][2];
  __shared__ int rfl[2];

  if (tid < 2) { seqAw[tid] = -1; rfl[tid] = -1; }
  if (tid < 6) sp[tid >> 1][tid & 1] = -1;
  if (tid < RPB * 2) stg[tid >> 1][tid & 1] = -1;
  for (int i = tid; i < LSQ; i += 512) E[i] = __expf(tr[i]);
  __syncthreads();  // the only block-wide barrier

  if (role != 0) {
    // ==================== relay pair, offset d in [5..63] ===================
    const int d = DMIN + RPB * (role - 1) + pair;
    if (d > Wn) return;
    const int j = d & 7;
    u64* chain = acc + (size_t)(j * 4 + b) * Tn * Ln;
    const u64* axB = axp + (size_t)b * Tn * Ln;
    float R[Ln];
#pragma unroll
    for (int lp = 0; lp < Ln; ++lp) R[lp] = E[lp * Ln + ln];
    int wc = 1;
    const bool aHead = (d + KCH > Wn);

    for (int t = d; t < Tn; ++t) {
      const int s = t - d;
      const int w = (t <= Wn) ? (s + 1) : (64 - d);
      if (w > wc) {
        wc = w;
#pragma unroll
        for (int lp = 0; lp < Ln; ++lp) R[lp] *= E[lp * Ln + ln];
      }
      const float segv = seg[SIDX(b, s + 1, t) + ln];  // hidden under gate
      const size_t tIdx = (size_t)t * Ln + ln;
      const bool head = aHead || (s < KCH);
      u64 ua = 0;
      if (!head) ua = __hip_atomic_load(&chain[tIdx], RLX, AGENT);  // early

      // gate: wave-wide data load of alpha[s], self-validating sentinel
      u64 up = __hip_atomic_load(&axB[(size_t)s * Ln + ln], RLX, AGENT);
      while ((u32)(up >> 32) == SENT)
        up = __hip_atomic_load(&axB[(size_t)s * Ln + ln], RLX, AGENT);

      const int buf = t & 1;
      if (act) Alb_s[pair][buf][tp] = __uint_as_float((u32)up);
      const float Cs = __uint_as_float((u32)(up >> 32));
      LDSF();
      __hip_atomic_store(&stg[pair][wv], t, RLX, WG);
      while (__hip_atomic_load(&stg[pair][wv ^ 1], RLX, WG) < t) {}
      CBAR();

      float i0 = 0, i1 = 0, i2 = 0, i3 = 0;
      const float4* A4 = (const float4*)Alb_s[pair][buf];
#pragma unroll
      for (int q = 0; q < 24; ++q) {
        float4 a = A4[q];
        i0 = fmaf(a.x, R[4 * q + 0], i0);
        i1 = fmaf(a.y, R[4 * q + 1], i1);
        i2 = fmaf(a.z, R[4 * q + 2], i2);
        i3 = fmaf(a.w, R[4 * q + 3], i3);
      }
      const float c = Cs + (float)w * segv + __logf((i0 + i1) + (i2 + i3));

      float m, v;
      if (head) {
        m = c;
        v = 1.f;
      } else {
        while (((ua >> 32) & 0xFFu) != (u32)(d + KCH))
          ua = __hip_atomic_load(&chain[tIdx], RLX, AGENT);
        const float pm = __uint_as_float((u32)ua);
        const float pv = __uint_as_float(((u32)(ua >> 32)) & ~0xFFu);
        const float nm = fmaxf(pm, c);
        v = pv * __expf(pm - nm) + __expf(c - nm);
        m = nm;
      }
      if (act) {
        const u32 vb = (__float_as_uint(v) & ~0xFFu) | (u32)d;
        __hip_atomic_store(&chain[tIdx],
                           (u64)__float_as_uint(m) | ((u64)vb << 32), RLX,
                           AGENT);
      }
    }
    return;
  }

  if (pair != 0) {
    // ============== in-block pair: offset d = pair+1 in {2,3,4} =============
    const int d = pair + 1;
    float R[Ln];
#pragma unroll
    for (int lp = 0; lp < Ln; ++lp) R[lp] = E[lp * Ln + ln];
    int wc = 1;
    for (int t = d; t < Tn; ++t) {
      const int s = t - d;
      const int w = (t <= Wn) ? (s + 1) : (64 - d);
      if (w > wc) {
        wc = w;
#pragma unroll
        for (int lp = 0; lp < Ln; ++lp) R[lp] *= E[lp * Ln + ln];
      }
      const float segv = seg[SIDX(b, s + 1, t) + ln];  // issue early
      while (__hip_atomic_load(&seqAw[0], RLX, WG) < s) {}
      while (__hip_atomic_load(&seqAw[1], RLX, WG) < s) {}
      CBAR();
      const float Cs = CRng[s & 7];
      float i0 = 0, i1 = 0, i2 = 0, i3 = 0;
      const float4* A4 = (const float4*)AlbR[s & 7];
#pragma unroll
      for (int q = 0; q < 24; ++q) {
        float4 a = A4[q];
        i0 = fmaf(a.x, R[4 * q + 0], i0);
        i1 = fmaf(a.y, R[4 * q + 1], i1);
        i2 = fmaf(a.z, R[4 * q + 2], i2);
        i3 = fmaf(a.w, R[4 * q + 3], i3);
      }
      const float c = Cs + (float)w * segv + __logf((i0 + i1) + (i2 + i3));
      if (act) slotC[t & 3][pair - 1][tp] = c;
      LDSF();
      __hip_atomic_store(&sp[pair - 1][wv], t, RLX, WG);
    }
    return;
  }

  // ================== pair 0: d=1 + global merge + publish ==================
  const float bos = tr[LSQ + ln];
  u64* axpB = axp + (size_t)b * Tn * Ln;
  float R1[Ln];
#pragma unroll
  for (int lp = 0; lp < Ln; ++lp) R1[lp] = E[lp * Ln + ln];
  int w1c = 1;
  const int endd[8] = {8, 9, 10, 11, 12, 5, 6, 7};  // chain end per residue

  {  // seed t=0: alpha0 = exp(seg[b,0,0,:]+bos) (reference stores exp'd value)
    const float a0 = __expf(seg[SIDX(b, 0, 0) + ln] + bos);
    const float wm = wmaxred(act ? a0 : NEGINF);
    if ((tp & 63) == 0) redbuf[0][wv] = wm;
    LDSF();
    __hip_atomic_store(&rfl[wv], 0, RLX, WG);
    while (__hip_atomic_load(&rfl[wv ^ 1], RLX, WG) < 0) {}
    CBAR();
    const float C0 = fmaxf(redbuf[0][0], redbuf[0][1]);
    const float ax0 = __expf(a0 - C0);
    if (act) AlbR[0][tp] = ax0;
    if (tid == 0) CRng[0] = C0;
    LDSF();
    __hip_atomic_store(&seqAw[wv], 0, RLX, WG);
    if (act) __hip_atomic_store(&axpB[tp], pack2(ax0, C0), RLX, AGENT);
  }

  for (int t = 1; t < Tn; ++t) {
    const int s = t - 1;
    // early loads for this step (8 independent MALL reads + 2 HBM reads)
    u64 u[8];
#pragma unroll
    for (int jj = 0; jj < 8; ++jj)
      if (t >= endd[jj])
        u[jj] = __hip_atomic_load(
            &acc[(((size_t)jj * 4 + b) * Tn + t) * Ln + ln], RLX, AGENT);
    const float s1 = seg[SIDX(b, t, t) + ln];
    const float szv = (t <= Wn) ? seg[SIDX(b, 0, t) + ln] : 0.f;

    const int w1 = (t <= Wn) ? t : Wn;
    if (w1 > w1c) {
      w1c = w1;
#pragma unroll
      for (int lp = 0; lp < Ln; ++lp) R1[lp] *= E[lp * Ln + ln];
    }
    while (__hip_atomic_load(&seqAw[wv ^ 1], RLX, WG) < s) {}
    CBAR();
    float i0 = 0, i1 = 0, i2 = 0, i3 = 0;
    const float4* A4 = (const float4*)AlbR[s & 7];
#pragma unroll
    for (int q = 0; q < 24; ++q) {
      float4 a = A4[q];
      i0 = fmaf(a.x, R1[4 * q + 0], i0);
      i1 = fmaf(a.y, R1[4 * q + 1], i1);
      i2 = fmaf(a.z, R1[4 * q + 2], i2);
      i3 = fmaf(a.w, R1[4 * q + 3], i3);
    }
    const float c1 =
        CRng[s & 7] + (float)w1 * s1 + __logf((i0 + i1) + (i2 + i3));

    // in-block contributions d=2,3,4
    float cc[3];
#pragma unroll
    for (int k = 1; k <= 3; ++k) {
      if (t >= k + 1) {
        while (__hip_atomic_load(&sp[k - 1][wv], RLX, WG) < t) {}
        cc[k - 1] = 0.f;  // placeholder, real read below after CBAR
      } else
        cc[k - 1] = NEGINF;
    }
    CBAR();
#pragma unroll
    for (int k = 1; k <= 3; ++k)
      if (t >= k + 1) cc[k - 1] = slotC[t & 3][k - 1][ln];

    // external chain ends
    float em[8], ev[8];
#pragma unroll
    for (int jj = 0; jj < 8; ++jj) {
      if (t >= endd[jj]) {
        const size_t aIdx = (((size_t)jj * 4 + b) * Tn + t) * Ln + ln;
        while (((u[jj] >> 32) & 0xFFu) != (u32)endd[jj])
          u[jj] = __hip_atomic_load(&acc[aIdx], RLX, AGENT);
        em[jj] = __uint_as_float((u32)u[jj]);
        ev[jj] = __uint_as_float(((u32)(u[jj] >> 32)) & ~0xFFu);
      } else {
        em[jj] = NEGINF;
        ev[jj] = 0.f;
      }
    }
    const float zv = (t <= Wn) ? (float)(t + 1) * (szv + bos) : NEGINF;

    // single-max LSE merge of {c1, cc[0..2], (em,ev)[0..7], zv}
    float M = c1;
#pragma unroll
    for (int k = 0; k < 3; ++k) M = fmaxf(M, cc[k]);
#pragma unroll
    for (int jj = 0; jj < 8; ++jj) M = fmaxf(M, em[jj]);
    M = fmaxf(M, zv);
    float vs = __expf(c1 - M) + __expf(zv - M);
#pragma unroll
    for (int k = 0; k < 3; ++k) vs += __expf(cc[k] - M);
#pragma unroll
    for (int jj = 0; jj < 8; ++jj) vs += ev[jj] * __expf(em[jj] - M);
    const float alpha = M + __logf(vs);

    // block-wide C = max(alpha) over 96 (pair0's two waves)
    const float wm = wmaxred(act ? alpha : NEGINF);
    if ((tp & 63) == 0) redbuf[t & 1][wv] = wm;
    LDSF();
    __hip_atomic_store(&rfl[wv], t, RLX, WG);
    while (__hip_atomic_load(&rfl[wv ^ 1], RLX, WG) < t) {}
    CBAR();
    const float C = fmaxf(redbuf[t & 1][0], redbuf[t & 1][1]);
    const float axn = __expf(alpha - C);
    if (act) AlbR[t & 7][tp] = axn;
    if (tid == 0) CRng[t & 7] = C;
    LDSF();
    __hip_atomic_store(&seqAw[wv], t, RLX, WG);
    if (act)
      __hip_atomic_store(&axpB[(size_t)t * Ln + tp], pack2(axn, C), RLX,
                         AGENT);

    if (t == Tn - 1) {
      const float sm = wsumred(act ? axn : 0.f);
      if ((tp & 63) == 0) redbuf[(t + 1) & 1][wv] = sm;
      LDSF();
      __hip_atomic_store(&rfl[wv], t + 1, RLX, WG);
      while (__hip_atomic_load(&rfl[wv ^ 1], RLX, WG) < t + 1) {}
      CBAR();
      if (tid == 0)
        out[b] = C + __logf(redbuf[(t + 1) & 1][0] + redbuf[(t + 1) & 1][1]);
    }
  }
}

extern "C" void kernel_launch(void* const* d_in, const int* in_sizes, int n_in,
                              void* d_out, int out_size, void* d_ws,
                              size_t ws_size, hipStream_t stream) {
  const float* seg = (const float*)d_in[0];  // (4,512,512,96) f32
  const float* tr = (const float*)d_in[1];   // (97,96) f32
  float* out = (float*)d_out;                // (4,) f32

  u64* axp = (u64*)d_ws;                 // [4][512][96]
  u64* acc = axp + (size_t)4 * Tn * Ln;  // [8][4][512][96]

  hipLaunchKernelGGL(init_ws, dim3(2048), dim3(256), 0, stream, (u64*)d_ws);
  hipLaunchKernelGGL(semicrf, dim3(4 * BPB), dim3(512), 0, stream, seg, tr,
                     out, axp, acc);
}

// Round 8
// 1025.146 us; speedup vs baseline: 2.2716x; 1.0639x over previous
//
#include <hip/hip_runtime.h>

// Semi-CRF log-partition. B=4, T=512, L=96, W=63.
// v8: LDS-bandwidth diet on the finalizer CU + shortened serial core.
//  - labels split [0,48)/[48,96) with per-half C (split-C publish, comb() at
//    consumers — removes the core's cross-wave C handshake entirely)
//  - finalizer block: waves 0-1 core (d=1, 48 lanes each), wave 2 = d=2
//    (dual-label, single wave), wave 3 = d=3, waves 4-5 REST pair (merge only,
//    no matvec). d>=4 all remote via 8 interleaved chains (endd 4..11).
//  - wave-max via DPP quad_perm/mirrors + 4 readlanes (~50cy vs ~300 shfl)
//  - depth-2 rolling seg prefetch; relaxed LDS flags + lgkmcnt(0) so global
//    loads stay in flight across steps (no vmcnt drains)
// Cross-block handoffs: 8B relaxed agent atomics, self-validating
// (NaN sentinel in axp hi word; chain tag in acc low mantissa bits of v).

#define Tn 512
#define Ln 96
#define HL 48
#define LSQ (Ln * Ln)
#define Wn 63
#define KCH 8
#define RPB 4
#define BPB 16
#define NEGINF (-1e30f)
#define SENT 0x7FC00000u

#define AGENT __HIP_MEMORY_SCOPE_AGENT
#define WG __HIP_MEMORY_SCOPE_WORKGROUP
#define RLX __ATOMIC_RELAXED

#define LDSF() asm volatile("s_waitcnt lgkmcnt(0)" ::: "memory")
#define CBAR() asm volatile("" ::: "memory")

#define SIDX(b, i, t) ((((size_t)(b) * Tn + (i)) * Tn + (t)) * Ln)

typedef unsigned long long u64;
typedef unsigned int u32;

__device__ __forceinline__ float wsumred(float v) {
#pragma unroll
  for (int m = 32; m >= 1; m >>= 1) v += __shfl_xor(v, m, 64);
  return v;
}
__device__ __forceinline__ u64 pack2(float lo, float hi) {
  return (u64)__float_as_uint(lo) | ((u64)__float_as_uint(hi) << 32);
}
// full-wave max: 4 DPP steps (max over 16) + 4 readlanes
__device__ __forceinline__ float wavemax48(float v) {
  int x;
  x = __builtin_amdgcn_update_dpp(__float_as_int(v), __float_as_int(v), 0xB1,
                                  0xF, 0xF, false);  // quad xor1
  v = fmaxf(v, __int_as_float(x));
  x = __builtin_amdgcn_update_dpp(__float_as_int(v), __float_as_int(v), 0x4E,
                                  0xF, 0xF, false);  // quad xor2
  v = fmaxf(v, __int_as_float(x));
  x = __builtin_amdgcn_update_dpp(__float_as_int(v), __float_as_int(v), 0x141,
                                  0xF, 0xF, false);  // half-mirror (8)
  v = fmaxf(v, __int_as_float(x));
  x = __builtin_amdgcn_update_dpp(__float_as_int(v), __float_as_int(v), 0x140,
                                  0xF, 0xF, false);  // mirror (16)
  v = fmaxf(v, __int_as_float(x));
  float r0 = __int_as_float(__builtin_amdgcn_readlane(__float_as_int(v), 0));
  float r1 = __int_as_float(__builtin_amdgcn_readlane(__float_as_int(v), 16));
  float r2 = __int_as_float(__builtin_amdgcn_readlane(__float_as_int(v), 32));
  float r3 = __int_as_float(__builtin_amdgcn_readlane(__float_as_int(v), 48));
  return fmaxf(fmaxf(r0, r1), fmaxf(r2, r3));
}
// split-C combine: c = Cm + wseg + log(e^(C0-Cm)*Slo + e^(C1-Cm)*Shi)
__device__ __forceinline__ float comb(float Slo, float Shi, float C0, float C1,
                                      float wseg) {
  const float Cm = fmaxf(C0, C1);
  return Cm + wseg + __logf(__expf(C0 - Cm) * Slo + __expf(C1 - Cm) * Shi);
}

// single-label matvec, split halves (lp<48 / lp>=48)
#define MV1(SRC, RR, SLO, SHI)                                       \
  float SLO, SHI;                                                    \
  {                                                                  \
    const float4* A4 = (const float4*)(SRC);                         \
    float a0 = 0, a1 = 0, a2 = 0, a3 = 0;                            \
    _Pragma("unroll") for (int q = 0; q < 12; ++q) {                 \
      float4 a = A4[q];                                              \
      a0 = fmaf(a.x, RR[4 * q + 0], a0);                             \
      a1 = fmaf(a.y, RR[4 * q + 1], a1);                             \
      a2 = fmaf(a.z, RR[4 * q + 2], a2);                             \
      a3 = fmaf(a.w, RR[4 * q + 3], a3);                             \
    }                                                                \
    SLO = (a0 + a1) + (a2 + a3);                                     \
    float b0 = 0, b1 = 0, b2 = 0, b3 = 0;                            \
    _Pragma("unroll") for (int q = 12; q < 24; ++q) {                \
      float4 a = A4[q];                                              \
      b0 = fmaf(a.x, RR[4 * q + 0], b0);                             \
      b1 = fmaf(a.y, RR[4 * q + 1], b1);                             \
      b2 = fmaf(a.z, RR[4 * q + 2], b2);                             \
      b3 = fmaf(a.w, RR[4 * q + 3], b3);                             \
    }                                                                \
    SHI = (b0 + b1) + (b2 + b3);                                     \
  }

__global__ void init_ws(u64* ws) {
  const size_t n1 = (size_t)4 * Tn * Ln;
  const size_t n = n1 * (1 + KCH);
  for (size_t i = (size_t)blockIdx.x * blockDim.x + threadIdx.x; i < n;
       i += (size_t)gridDim.x * blockDim.x)
    ws[i] = (i < n1) ? (((u64)SENT) << 32) : 0ull;
}

__global__ __launch_bounds__(512, 1) void semicrf(
    const float* __restrict__ seg, const float* __restrict__ tr,
    float* __restrict__ out, u64* axp, u64* acc) {
  const int b = blockIdx.x / BPB;
  const int role = blockIdx.x % BPB;
  const int tid = threadIdx.x;
  const int w6 = tid >> 6;
  const int l = tid & 63;

  __shared__ __align__(16) float E[LSQ];          // exp(trans) 36 KB
  __shared__ __align__(16) float AlbR[8][Ln];     // core alpha ring
  __shared__ float CRng[8][2];                    // per-half C ring
  __shared__ __align__(16) float slotC[4][2][Ln]; // d=2,3 contributions
  __shared__ float RESTm[4][Ln];                  // REST merge (m)
  __shared__ float RESTv[4][Ln];                  // REST merge (v)
  __shared__ __align__(16) float Alb_s[RPB][2][Ln];  // relay staging
  __shared__ float CstS[RPB][2][2];
  __shared__ float redbuf[2];
  __shared__ int seqA[2], sp[2], rq[2], rfl[2];
  __shared__ int stg[RPB][2];

  if (tid < 2) { seqA[tid] = -1; rq[tid] = -1; rfl[tid] = -1; sp[tid] = -1; }
  if (tid < RPB * 2) stg[tid >> 1][tid & 1] = -1;
  for (int i = tid; i < LSQ; i += 512) E[i] = __expf(tr[i]);
  __syncthreads();  // only block-wide barrier

  if (role != 0) {
    // ========== relay pair, offset d in [4..63], 8 chains (d mod 8) =========
    const int pair = tid >> 7;
    const int tp = tid & 127;
    const int wv = tp >> 6;
    const int rl = tp & 63;
    const bool act = rl < HL;
    const int lab = wv * HL + (act ? rl : HL - 1);
    const int d = 4 + RPB * (role - 1) + pair;  // 4..63 exactly
    const int j = d & 7;
    u64* chain = acc + (size_t)(j * 4 + b) * Tn * Ln;
    const u64* axB = axp + (size_t)b * Tn * Ln;
    float R[Ln];
#pragma unroll
    for (int lp = 0; lp < Ln; ++lp) R[lp] = E[lp * Ln + lab];
    int wc = 1;
    const bool aHead = (d + KCH > Wn);

    for (int t = d; t < Tn; ++t) {
      const int s = t - d;
      const int w = (t <= Wn) ? (s + 1) : (64 - d);
      if (w > wc) {
        wc = w;
#pragma unroll
        for (int lp = 0; lp < Ln; ++lp) R[lp] *= E[lp * Ln + lab];
      }
      const float segv = seg[SIDX(b, s + 1, t) + lab];  // hidden under gate
      const size_t tIdx = (size_t)t * Ln + lab;
      const bool head = aHead || (s < KCH);
      u64 ua = 0;
      if (!head) ua = __hip_atomic_load(&chain[tIdx], RLX, AGENT);  // early

      u64 up = __hip_atomic_load(&axB[(size_t)s * Ln + lab], RLX, AGENT);
      while ((u32)(up >> 32) == SENT)
        up = __hip_atomic_load(&axB[(size_t)s * Ln + lab], RLX, AGENT);

      const int buf = t & 1;
      if (act) Alb_s[pair][buf][lab] = __uint_as_float((u32)up);
      if (rl == 0) CstS[pair][buf][wv] = __uint_as_float((u32)(up >> 32));
      LDSF();
      __hip_atomic_store(&stg[pair][wv], t, RLX, WG);
      while (__hip_atomic_load(&stg[pair][wv ^ 1], RLX, WG) < t) {}
      CBAR();
      const float C0 = CstS[pair][buf][0], C1 = CstS[pair][buf][1];
      MV1(Alb_s[pair][buf], R, Slo, Shi)
      const float c = comb(Slo, Shi, C0, C1, (float)w * segv);

      float m, v;
      if (head) {
        m = c;
        v = 1.f;
      } else {
        while (((ua >> 32) & 0xFFu) != (u32)(d + KCH))
          ua = __hip_atomic_load(&chain[tIdx], RLX, AGENT);
        const float pm = __uint_as_float((u32)ua);
        const float pv = __uint_as_float(((u32)(ua >> 32)) & ~0xFFu);
        const float nm = fmaxf(pm, c);
        v = pv * __expf(pm - nm) + __expf(c - nm);
        m = nm;
      }
      if (act) {
        const u32 vb = (__float_as_uint(v) & ~0xFFu) | (u32)d;
        __hip_atomic_store(&chain[tIdx],
                           (u64)__float_as_uint(m) | ((u64)vb << 32), RLX,
                           AGENT);
      }
    }
    return;
  }

  if (w6 >= 6) return;  // waves 6,7 unused in finalizer

  if (w6 < 2) {
    // ============== CORE: d=1, wave cwv owns labels [cwv*48, +48) ===========
    const int cwv = w6;
    const bool act = l < HL;
    const int lab = cwv * HL + (act ? l : HL - 1);
    const float bos = tr[LSQ + lab];
    u64* axpB = axp + (size_t)b * Tn * Ln;
    float R1[Ln];
#pragma unroll
    for (int lp = 0; lp < Ln; ++lp) R1[lp] = E[lp * Ln + lab];
    int w1c = 1;

    {  // seed t=0: alpha0 = exp(seg[b,0,0,:]+bos) (reference stores exp'd)
      const float a0 = __expf(seg[SIDX(b, 0, 0) + lab] + bos);
      const float Cw = wavemax48(act ? a0 : NEGINF);
      const float ax0 = __expf(a0 - Cw);
      if (act) AlbR[0][lab] = ax0;
      if (l == 0) CRng[0][cwv] = Cw;
      LDSF();
      __hip_atomic_store(&seqA[cwv], 0, RLX, WG);
      if (act) __hip_atomic_store(&axpB[lab], pack2(ax0, Cw), RLX, AGENT);
    }
    float s1q0 = seg[SIDX(b, 1, 1) + lab];
    float s1q1 = seg[SIDX(b, 2, 2) + lab];

    for (int t = 1; t < Tn; ++t) {
      const int s = t - 1;
      const float s1 = s1q0;
      s1q0 = s1q1;
      if (t + 2 < Tn) s1q1 = seg[SIDX(b, t + 2, t + 2) + lab];
      const int w1 = (t <= Wn) ? t : Wn;
      if (w1 > w1c) {
        w1c = w1;
#pragma unroll
        for (int lp = 0; lp < Ln; ++lp) R1[lp] *= E[lp * Ln + lab];
      }
      while (__hip_atomic_load(&seqA[cwv ^ 1], RLX, WG) < s) {}
      CBAR();
      const float C0 = CRng[s & 7][0], C1 = CRng[s & 7][1];
      MV1(AlbR[s & 7], R1, Slo, Shi)
      const float c1 = comb(Slo, Shi, C0, C1, (float)w1 * s1);
      while (__hip_atomic_load(&rq[cwv], RLX, WG) < t) {}
      CBAR();
      const float mr = RESTm[t & 3][lab], vr = RESTv[t & 3][lab];
      const float nm = fmaxf(c1, mr);
      const float vv = __expf(c1 - nm) + vr * __expf(mr - nm);
      const float alpha = nm + __logf(vv);
      const float Cw = wavemax48(act ? alpha : NEGINF);
      const float axn = __expf(alpha - Cw);
      if (act) AlbR[t & 7][lab] = axn;
      if (l == 0) CRng[t & 7][cwv] = Cw;
      LDSF();
      __hip_atomic_store(&seqA[cwv], t, RLX, WG);
      if (act)
        __hip_atomic_store(&axpB[(size_t)t * Ln + lab], pack2(axn, Cw), RLX,
                           AGENT);
      if (t == Tn - 1) {
        const float sm = wsumred(act ? axn : 0.f);
        const float Gw = Cw + __logf(sm);
        if (l == 0) redbuf[cwv] = Gw;
        LDSF();
        __hip_atomic_store(&rfl[cwv], 1, RLX, WG);
        if (cwv == 0 && l == 0) {
          while (__hip_atomic_load(&rfl[1], RLX, WG) < 1) {}
          CBAR();
          const float G0 = redbuf[0], G1 = redbuf[1];
          const float Mx = fmaxf(G0, G1);
          out[b] = Mx + __logf(__expf(G0 - Mx) + __expf(G1 - Mx));
        }
      }
    }
    return;
  }

  if (w6 == 2 || w6 == 3) {
    // ====== dual-label offset wave: d = w6 (2 or 3), labels l and l+48 ======
    const int d = w6;
    const bool act = l < HL;
    const int la = act ? l : HL - 1;
    const int lb = la + HL;
    float Ra[Ln], Rb[Ln];
#pragma unroll
    for (int lp = 0; lp < Ln; ++lp) {
      Ra[lp] = E[lp * Ln + la];
      Rb[lp] = E[lp * Ln + lb];
    }
    int wc = 1;
    float qa0 = seg[SIDX(b, 1, d) + la], qb0 = seg[SIDX(b, 1, d) + lb];
    float qa1 = seg[SIDX(b, 2, d + 1) + la], qb1 = seg[SIDX(b, 2, d + 1) + lb];

    for (int t = d; t < Tn; ++t) {
      const int s = t - d;
      const int w = (t <= Wn) ? (s + 1) : (64 - d);
      if (w > wc) {
        wc = w;
#pragma unroll
        for (int lp = 0; lp < Ln; ++lp) {
          Ra[lp] *= E[lp * Ln + la];
          Rb[lp] *= E[lp * Ln + lb];
        }
      }
      const float sa = qa0, sb = qb0;
      qa0 = qa1;
      qb0 = qb1;
      if (t + 2 < Tn) {
        qa1 = seg[SIDX(b, t + 3 - d, t + 2) + la];
        qb1 = seg[SIDX(b, t + 3 - d, t + 2) + lb];
      }
      while (__hip_atomic_load(&seqA[0], RLX, WG) < s) {}
      while (__hip_atomic_load(&seqA[1], RLX, WG) < s) {}
      CBAR();
      const float C0 = CRng[s & 7][0], C1 = CRng[s & 7][1];
      // dual-label matvec in one pass over the ring
      float alo0 = 0, alo1 = 0, blo0 = 0, blo1 = 0;
      float ahi0 = 0, ahi1 = 0, bhi0 = 0, bhi1 = 0;
      const float4* A4 = (const float4*)AlbR[s & 7];
#pragma unroll
      for (int q = 0; q < 12; ++q) {
        float4 a = A4[q];
        alo0 = fmaf(a.x, Ra[4 * q + 0], alo0);
        alo1 = fmaf(a.y, Ra[4 * q + 1], alo1);
        alo0 = fmaf(a.z, Ra[4 * q + 2], alo0);
        alo1 = fmaf(a.w, Ra[4 * q + 3], alo1);
        blo0 = fmaf(a.x, Rb[4 * q + 0], blo0);
        blo1 = fmaf(a.y, Rb[4 * q + 1], blo1);
        blo0 = fmaf(a.z, Rb[4 * q + 2], blo0);
        blo1 = fmaf(a.w, Rb[4 * q + 3], blo1);
      }
#pragma unroll
      for (int q = 12; q < 24; ++q) {
        float4 a = A4[q];
        ahi0 = fmaf(a.x, Ra[4 * q + 0], ahi0);
        ahi1 = fmaf(a.y, Ra[4 * q + 1], ahi1);
        ahi0 = fmaf(a.z, Ra[4 * q + 2], ahi0);
        ahi1 = fmaf(a.w, Ra[4 * q + 3], ahi1);
        bhi0 = fmaf(a.x, Rb[4 * q + 0], bhi0);
        bhi1 = fmaf(a.y, Rb[4 * q + 1], bhi1);
        bhi0 = fmaf(a.z, Rb[4 * q + 2], bhi0);
        bhi1 = fmaf(a.w, Rb[4 * q + 3], bhi1);
      }
      const float ca = comb(alo0 + alo1, ahi0 + ahi1, C0, C1, (float)w * sa);
      const float cb = comb(blo0 + blo1, bhi0 + bhi1, C0, C1, (float)w * sb);
      if (act) {
        slotC[t & 3][d - 2][la] = ca;
        slotC[t & 3][d - 2][lb] = cb;
      }
      LDSF();
      __hip_atomic_store(&sp[d - 2], t, RLX, WG);
    }
    return;
  }

  {
    // ========= REST pair (waves 4,5): chains + slotC + z merge only =========
    const int rwv = w6 - 4;
    const bool act = l < HL;
    const int lab = rwv * HL + (act ? l : HL - 1);
    const float bos = tr[LSQ + lab];
    const int endd[8] = {8, 9, 10, 11, 4, 5, 6, 7};  // chain end per residue
    float zq0 = seg[SIDX(b, 0, 1) + lab];
    float zq1 = seg[SIDX(b, 0, 2) + lab];

    for (int t = 1; t < Tn; ++t) {
      u64 u[8];
#pragma unroll
      for (int jj = 0; jj < 8; ++jj)
        if (t >= endd[jj])
          u[jj] = __hip_atomic_load(
              &acc[(((size_t)jj * 4 + b) * Tn + t) * Ln + lab], RLX, AGENT);
      const float szv = zq0;
      zq0 = zq1;
      if (t + 2 <= Wn) zq1 = seg[SIDX(b, 0, t + 2) + lab];

      float cc0 = NEGINF, cc1 = NEGINF;
      if (t >= 2) {
        while (__hip_atomic_load(&sp[0], RLX, WG) < t) {}
      }
      if (t >= 3) {
        while (__hip_atomic_load(&sp[1], RLX, WG) < t) {}
      }
      CBAR();
      if (t >= 2) cc0 = slotC[t & 3][0][lab];
      if (t >= 3) cc1 = slotC[t & 3][1][lab];

      float em[8], ev[8];
#pragma unroll
      for (int jj = 0; jj < 8; ++jj) {
        if (t >= endd[jj]) {
          const size_t aIdx = (((size_t)jj * 4 + b) * Tn + t) * Ln + lab;
          while (((u[jj] >> 32) & 0xFFu) != (u32)endd[jj])
            u[jj] = __hip_atomic_load(&acc[aIdx], RLX, AGENT);
          em[jj] = __uint_as_float((u32)u[jj]);
          ev[jj] = __uint_as_float(((u32)(u[jj] >> 32)) & ~0xFFu);
        } else {
          em[jj] = NEGINF;
          ev[jj] = 0.f;
        }
      }
      const float zv = (t <= Wn) ? (float)(t + 1) * (szv + bos) : NEGINF;

      float M = fmaxf(fmaxf(cc0, cc1), zv);
#pragma unroll
      for (int jj = 0; jj < 8; ++jj) M = fmaxf(M, em[jj]);
      float vs = __expf(cc0 - M) + __expf(cc1 - M) + __expf(zv - M);
#pragma unroll
      for (int jj = 0; jj < 8; ++jj) vs += ev[jj] * __expf(em[jj] - M);

      if (act) {
        RESTm[t & 3][lab] = M;
        RESTv[t & 3][lab] = vs;
      }
      LDSF();
      __hip_atomic_store(&rq[rwv], t, RLX, WG);
    }
    return;
  }
}

extern "C" void kernel_launch(void* const* d_in, const int* in_sizes, int n_in,
                              void* d_out, int out_size, void* d_ws,
                              size_t ws_size, hipStream_t stream) {
  const float* seg = (const float*)d_in[0];  // (4,512,512,96) f32
  const float* tr = (const float*)d_in[1];   // (97,96) f32
  float* out = (float*)d_out;                // (4,) f32

  u64* axp = (u64*)d_ws;                 // [4][512][96]
  u64* acc = axp + (size_t)4 * Tn * Ln;  // [8][4][512][96]

  hipLaunchKernelGGL(init_ws, dim3(2048), dim3(256), 0, stream, (u64*)d_ws);
  hipLaunchKernelGGL(semicrf, dim3(4 * BPB), dim3(512), 0, stream, seg, tr,
                     out, axp, acc);
}